// Round 1
// baseline (207.537 us; speedup 1.0000x reference)
//
#include <hip/hip_runtime.h>

#define NB 2048
#define DD 128
#define HH 256
#define KF 32768   /* HH*DD */
#define LN_EPS 1e-5f

typedef __attribute__((ext_vector_type(8))) short short8;
typedef __attribute__((ext_vector_type(4))) float float4_t;

__device__ __forceinline__ unsigned short f2bf(float f) {
    unsigned int u = __builtin_bit_cast(unsigned int, f);
    u += 0x7fffu + ((u >> 16) & 1u);   // RNE
    return (unsigned short)(u >> 16);
}

__device__ __forceinline__ void gl2lds16(const void* g, void* l) {
    __builtin_amdgcn_global_load_lds(
        (const __attribute__((address_space(1))) unsigned int*)g,
        (__attribute__((address_space(3))) unsigned int*)l, 16, 0, 0);
}

// ---------------------------------------------------------------------------
// Kernel 1: Wh [32768,256] f32 (k = h*128+d major) -> WhbT [256][32768] bf16
// with K reordered to kappa = d*256 + h.  64x64 tiles via LDS.
// ---------------------------------------------------------------------------
__global__ void prep_b(const float* __restrict__ Wh, unsigned short* __restrict__ WhbT) {
    __shared__ unsigned short tile[64][65];
    int kb = blockIdx.x;          // kappa-tile 0..511
    int jb = blockIdx.y;          // j-tile 0..3
    int t = threadIdx.x;          // 256
    int c = t & 63, r4 = t >> 6;
    int kap0 = kb * 64;
    int d  = kap0 >> 8;           // fixed within a 64-aligned kappa tile
    int h0 = kap0 & 255;
    for (int rr = r4; rr < 64; rr += 4) {
        int k = (h0 + rr) * 128 + d;
        tile[rr][c] = f2bf(Wh[(long)k * 256 + jb * 64 + c]);
    }
    __syncthreads();
    for (int rr = r4; rr < 64; rr += 4) {
        WhbT[(long)(jb * 64 + rr) * KF + kap0 + c] = tile[c][rr];
    }
}

// ---------------------------------------------------------------------------
// Kernel 2: z-gen.  z[n][kappa=d*256+h] = LN_d(relu(a[n,d]*Win[d,h]+bin[d,h]))
// Block handles 4 n's; thread = h.  Attention branch dropped (LN-invariant).
// ---------------------------------------------------------------------------
__global__ void zgen(const float* __restrict__ arr, const float* __restrict__ Win,
                     const float* __restrict__ bin, const float* __restrict__ g,
                     const float* __restrict__ beta, unsigned short* __restrict__ Z) {
    __shared__ float a_s[4][128];
    __shared__ float g_s[128], b_s[128];
    int t = threadIdx.x;
    int n0 = blockIdx.x * 4;
    if (t < 128) { g_s[t] = g[t]; b_s[t] = beta[t]; }
    for (int i = t; i < 512; i += 256) a_s[i >> 7][i & 127] = arr[n0 * 128 + i];
    __syncthreads();
    int h = t;
    float sum[4] = {0.f, 0.f, 0.f, 0.f}, ssq[4] = {0.f, 0.f, 0.f, 0.f};
    for (int d = 0; d < 128; ++d) {
        float w = Win[d * 256 + h];
        float bb = bin[d * 256 + h];
#pragma unroll
        for (int q = 0; q < 4; ++q) {
            float x = fmaxf(fmaf(a_s[q][d], w, bb), 0.f);
            sum[q] += x; ssq[q] += x * x;
        }
    }
    float mu[4], rs[4];
#pragma unroll
    for (int q = 0; q < 4; ++q) {
        mu[q] = sum[q] * (1.f / 128.f);
        float var = fmaxf(ssq[q] * (1.f / 128.f) - mu[q] * mu[q], 0.f);
        rs[q] = rsqrtf(var + LN_EPS);
    }
    for (int d = 0; d < 128; ++d) {
        float w = Win[d * 256 + h];
        float bb = bin[d * 256 + h];
        float gg = g_s[d], be = b_s[d];
#pragma unroll
        for (int q = 0; q < 4; ++q) {
            float x = fmaxf(fmaf(a_s[q][d], w, bb), 0.f);
            float zv = fmaf((x - mu[q]) * rs[q], gg, be);
            Z[(long)(n0 + q) * KF + d * 256 + h] = f2bf(zv);
        }
    }
}

// ---------------------------------------------------------------------------
// Kernel 3: GEMM  C[2048,256] = Z[2048,KF] * Whb[KF,256], both K-contiguous
// bf16, MFMA 16x16x32, tiles BM=BN=128, BK=32, split-K=16 -> fp32 partials.
// ---------------------------------------------------------------------------
#define BM 128
#define BN 128
#define BK 32
#define KSPLIT 16
#define KSL (KF / KSPLIT)   /* 2048 */

__global__ __launch_bounds__(256, 2) void gemm_k(
        const unsigned short* __restrict__ A,    // Z  [2048][KF]
        const unsigned short* __restrict__ Bt,   // WhbT [256][KF]
        float* __restrict__ Cp) {
    __shared__ unsigned short As[BM * BK];   // [row][k] row-major, 8KB
    __shared__ unsigned short Bs[BN * BK];   // [j][k]  row-major, 8KB
    int bid = blockIdx.x;
    int ks = bid >> 5;          // 0..15 k-slice
    int mt = (bid >> 1) & 15;   // 0..15
    int nt = bid & 1;           // 0..1
    int m0 = mt * BM, n0 = nt * BN, k0 = ks * KSL;
    int t = threadIdx.x;
    int lane = t & 63, wave = t >> 6;
    int wm = (wave >> 1) * 64, wn = (wave & 1) * 64;
    int fr = lane & 15;
    int fk = (lane >> 4) * 8;

    float4_t acc[4][4] = {};

    const unsigned short* Aab = A + (long)m0 * KF + k0;
    const unsigned short* Bab = Bt + (long)n0 * KF + k0;
    int s0 = t, s1 = t + 256;
    long aoff0 = (long)(s0 >> 2) * KF + (long)(s0 & 3) * 8;
    long aoff1 = (long)(s1 >> 2) * KF + (long)(s1 & 3) * 8;

    for (int kk = 0; kk < KSL; kk += BK) {
        __syncthreads();
        gl2lds16(Aab + kk + aoff0, &As[s0 * 8]);
        gl2lds16(Aab + kk + aoff1, &As[s1 * 8]);
        gl2lds16(Bab + kk + aoff0, &Bs[s0 * 8]);
        gl2lds16(Bab + kk + aoff1, &Bs[s1 * 8]);
        __syncthreads();
        short8 af[4], bfv[4];
#pragma unroll
        for (int i = 0; i < 4; ++i)
            af[i] = *(const short8*)&As[(wm + i * 16 + fr) * BK + fk];
#pragma unroll
        for (int i = 0; i < 4; ++i)
            bfv[i] = *(const short8*)&Bs[(wn + i * 16 + fr) * BK + fk];
#pragma unroll
        for (int mi = 0; mi < 4; ++mi)
#pragma unroll
            for (int ni = 0; ni < 4; ++ni)
                acc[mi][ni] = __builtin_amdgcn_mfma_f32_16x16x32_bf16(
                    af[mi], bfv[ni], acc[mi][ni], 0, 0, 0);
    }

    // epilogue: C/D layout col=lane&15, row=(lane>>4)*4+reg  [m89-verified]
    int rb = (lane >> 4) * 4;
    float* Cb = Cp + (long)ks * NB * 256;
#pragma unroll
    for (int mi = 0; mi < 4; ++mi) {
#pragma unroll
        for (int ni = 0; ni < 4; ++ni) {
            int n = n0 + wn + ni * 16 + fr;
#pragma unroll
            for (int r = 0; r < 4; ++r) {
                int m = m0 + wm + mi * 16 + rb + r;
                Cb[(long)m * 256 + n] = acc[mi][ni][r];
            }
        }
    }
}

// ---------------------------------------------------------------------------
// Kernel 4: out[n] = bo + sum_j Wo[j]*relu(bh[j] + sum_s Cp[s][n][j])
// ---------------------------------------------------------------------------
__global__ void finale(const float* __restrict__ Cp, const float* __restrict__ bh,
                       const float* __restrict__ Wo, const float* __restrict__ bo,
                       float* __restrict__ out) {
    __shared__ float red[4];
    int n = blockIdx.x, t = threadIdx.x;
    int lane = t & 63, wave = t >> 6;
    float s = bh[t];
    for (int sl = 0; sl < KSPLIT; ++sl)
        s += Cp[(long)sl * NB * 256 + (long)n * 256 + t];
    float v = fmaxf(s, 0.f) * Wo[t];
#pragma unroll
    for (int o = 32; o; o >>= 1) v += __shfl_down(v, o);
    if (lane == 0) red[wave] = v;
    __syncthreads();
    if (t == 0) out[n] = red[0] + red[1] + red[2] + red[3] + bo[0];
}

extern "C" void kernel_launch(void* const* d_in, const int* in_sizes, int n_in,
                              void* d_out, int out_size, void* d_ws, size_t ws_size,
                              hipStream_t stream) {
    const float* arr  = (const float*)d_in[0];
    const float* Win  = (const float*)d_in[1];
    const float* bin  = (const float*)d_in[2];
    const float* ln_g = (const float*)d_in[7];
    const float* ln_b = (const float*)d_in[8];
    const float* Wh   = (const float*)d_in[9];
    const float* bh   = (const float*)d_in[10];
    const float* Wo   = (const float*)d_in[11];
    const float* bo   = (const float*)d_in[12];
    float* out = (float*)d_out;

    char* ws = (char*)d_ws;
    unsigned short* WhbT = (unsigned short*)ws;                       // 16,777,216 B
    unsigned short* Z    = (unsigned short*)(ws + 16777216ull);       // 134,217,728 B
    float* Cp            = (float*)(ws + 16777216ull + 134217728ull); // 33,554,432 B

    hipLaunchKernelGGL(prep_b, dim3(512, 4), dim3(256), 0, stream, Wh, WhbT);
    hipLaunchKernelGGL(zgen, dim3(512), dim3(256), 0, stream, arr, Win, bin, ln_g, ln_b, Z);
    hipLaunchKernelGGL(gemm_k, dim3(512), dim3(256), 0, stream, Z, WhbT, Cp);
    hipLaunchKernelGGL(finale, dim3(NB), dim3(256), 0, stream, Cp, bh, Wo, bo, out);
}